// Round 2
// 725.375 us; speedup vs baseline: 1.0205x; 1.0205x over previous
//
#include <hip/hip_runtime.h>
#include <math.h>

#define BB 16
#define CC 128
#define HH 224
#define WW 224
#define HW (HH * WW)            // 50176
#define CHW (CC * HW)           // 6422528
#define TOTAL (BB * CHW)        // 102760448
#define TILE 64                 // spatial positions per fused block (HW % 64 == 0)

// Raw clang vector type: accepted by __builtin_nontemporal_load/store
// (HIP_vector_type float4 is a struct and is rejected).
typedef float f4 __attribute__((ext_vector_type(4)));

// Kernel 1: channel pool (max + mean over C) -> pooled [B, 2, H, W]
// One thread per 4 consecutive spatial positions (float4).
// x is read-once streaming -> nontemporal loads; pooled stays cached for kernel 2.
__global__ void pool_kernel(const float* __restrict__ x, float* __restrict__ pooled) {
    int tid = blockIdx.x * blockDim.x + threadIdx.x;      // [0, B*HW/4)
    int b = tid / (HW / 4);
    int r = (tid - b * (HW / 4)) * 4;                     // spatial offset within image
    const f4* xp = (const f4*)(x + (size_t)b * CHW + r);
    f4 v = __builtin_nontemporal_load(xp);
    f4 mx = v;
    f4 sm = v;
    #pragma unroll 8
    for (int c = 1; c < CC; ++c) {
        v = __builtin_nontemporal_load(xp + (size_t)c * (HW / 4));
        mx.x = fmaxf(mx.x, v.x); mx.y = fmaxf(mx.y, v.y);
        mx.z = fmaxf(mx.z, v.z); mx.w = fmaxf(mx.w, v.w);
        sm.x += v.x; sm.y += v.y; sm.z += v.z; sm.w += v.w;
    }
    const float inv = 1.0f / (float)CC;
    sm.x *= inv; sm.y *= inv; sm.z *= inv; sm.w *= inv;
    float* base = pooled + (size_t)b * 2 * HW + r;
    *(f4*)(base) = mx;            // channel 0: max
    *(f4*)(base + HW) = sm;       // channel 1: mean
}

// Kernel 2 (fused): 3x3 conv (2->1 ch, pad 1) + bias + sigmoid computed ONCE per
// spatial position into LDS, then all 128 channels of x are scaled by it.
// Block = 256 threads <-> one tile of 64 consecutive spatial positions in one image.
//   Phase A: threads 0..63 each compute one conv+sigmoid -> ls[64].
//   Phase B: lane f = t&15 owns float4 (4 positions), cg = t>>4 owns channel group;
//            8 iterations cover all 128 channels with independent in-flight loads.
__global__ void fused_conv_mult(const float* __restrict__ x,
                                const float* __restrict__ pooled,
                                const float* __restrict__ cw,
                                const float* __restrict__ cb,
                                float* __restrict__ out) {
    __shared__ float ls[TILE];
    int blk = blockIdx.x;                  // [0, B * HW/TILE)
    int b = blk / (HW / TILE);
    int t0 = (blk - b * (HW / TILE)) * TILE;
    int t = threadIdx.x;

    if (t < TILE) {
        int p = t0 + t;
        int h = p / WW;
        int w = p - h * WW;
        const float* pb = pooled + (size_t)b * 2 * HW;
        float acc = cb[0];
        #pragma unroll
        for (int ic = 0; ic < 2; ++ic) {
            const float* pp = pb + ic * HW;
            #pragma unroll
            for (int kh = 0; kh < 3; ++kh) {
                int hh = h + kh - 1;
                if (hh < 0 || hh >= HH) continue;
                #pragma unroll
                for (int kw = 0; kw < 3; ++kw) {
                    int ww2 = w + kw - 1;
                    if (ww2 < 0 || ww2 >= WW) continue;
                    acc += pp[hh * WW + ww2] * cw[ic * 9 + kh * 3 + kw];
                }
            }
        }
        ls[t] = 1.0f / (1.0f + __expf(-acc));
    }
    __syncthreads();

    int f = t & 15;                        // which float4 within the 64-pos tile
    int cg = t >> 4;                       // channel group 0..15
    f4 sv = *(const f4*)(ls + f * 4);      // 2 lanes/bank -> conflict-free broadcast
    const float* xb = x + (size_t)b * CHW + t0 + f * 4;
    float* ob = out + (size_t)b * CHW + t0 + f * 4;
    #pragma unroll
    for (int j = 0; j < 8; ++j) {
        size_t off = (size_t)(cg + j * 16) * HW;
        f4 xv = __builtin_nontemporal_load((const f4*)(xb + off));
        f4 ov;
        ov.x = xv.x * sv.x; ov.y = xv.y * sv.y;
        ov.z = xv.z * sv.z; ov.w = xv.w * sv.w;
        __builtin_nontemporal_store(ov, (f4*)(ob + off));
    }
}

extern "C" void kernel_launch(void* const* d_in, const int* in_sizes, int n_in,
                              void* d_out, int out_size, void* d_ws, size_t ws_size,
                              hipStream_t stream) {
    const float* x  = (const float*)d_in[0];
    const float* cw = (const float*)d_in[1];   // [1,2,3,3] = 18 floats
    const float* cb = (const float*)d_in[2];   // [1]
    float* out = (float*)d_out;

    float* pooled = (float*)d_ws;              // B*2*HW = 1605632 floats (6.4 MB)

    // Kernel 1: B*HW/4 = 200704 threads
    pool_kernel<<<(BB * HW / 4) / 256, 256, 0, stream>>>(x, pooled);
    // Kernel 2: one block per 64 spatial positions per image = 12544 blocks
    fused_conv_mult<<<BB * (HW / TILE), 256, 0, stream>>>(x, pooled, cw, cb, out);
}